// Round 2
// baseline (586.623 us; speedup 1.0000x reference)
//
#include <hip/hip_runtime.h>

#define NB 32
#define NA 8400
#define NG 64
#define NC 80
#define NK 13

// output offsets (floats) in d_out
#define OFF_LBL  0
#define OFF_BBOX 21504000
#define OFF_SCR  22579200
#define OFF_FG   44083200

__device__ __forceinline__ float sigmoid_f(float x) {
    return 1.0f / (1.0f + expf(-x));
}

__device__ __forceinline__ float iou_from_corners(
    float px1, float py1, float px2, float py2, float ap,
    float gx1, float gy1, float gx2, float gy2, float ag)
{
    float ix1 = fmaxf(px1, gx1), iy1 = fmaxf(py1, gy1);
    float ix2 = fminf(px2, gx2), iy2 = fminf(py2, gy2);
    float iw = fmaxf(ix2 - ix1, 0.0f), ih = fmaxf(iy2 - iy1, 0.0f);
    float inter = iw * ih;
    float uni = ap + ag - inter + 1e-7f;
    return inter / uni;
}

// ---------------- Kernel 1: per-(b,g) top-13 anchors ----------------
__global__ __launch_bounds__(256) void topk_kernel(
    const float* __restrict__ pd_scores,   // [B,A,C]
    const float* __restrict__ pd_bboxes,   // [B,A,4]
    const int* __restrict__ gt_labels,     // [B,G]
    const float* __restrict__ gt_bboxes,   // [B,G,4]
    const int* __restrict__ mask_gt,       // [B,G]  (bool uploaded as int32)
    int* __restrict__ topk_idx)            // [B,G,K]
{
    const int g = blockIdx.x;
    const int b = blockIdx.y;
    const int tid = threadIdx.x;
    int* out = topk_idx + (b * NG + g) * NK;

    const bool valid = mask_gt[b * NG + g] != 0;
    if (!valid) {
        if (tid < NK) out[tid] = -1;   // sentinel: matches no anchor
        return;                         // block-uniform early-exit
    }

    __shared__ float sm[NA];
    __shared__ float wv[4];
    __shared__ int   wi[4];

    const int label = gt_labels[b * NG + g];
    const float4 gb = *reinterpret_cast<const float4*>(gt_bboxes + (size_t)(b * NG + g) * 4);
    const float gx1 = gb.x - gb.z * 0.5f, gy1 = gb.y - gb.w * 0.5f;
    const float gx2 = gb.x + gb.z * 0.5f, gy2 = gb.y + gb.w * 0.5f;
    const float ag = (gx2 - gx1) * (gy2 - gy1);

    for (int a = tid; a < NA; a += 256) {
        const float4 pb = *reinterpret_cast<const float4*>(pd_bboxes + ((size_t)b * NA + a) * 4);
        const float px1 = pb.x - pb.z * 0.5f, py1 = pb.y - pb.w * 0.5f;
        const float px2 = pb.x + pb.z * 0.5f, py2 = pb.y + pb.w * 0.5f;
        const float ap = (px2 - px1) * (py2 - py1);
        const float iou = iou_from_corners(px1, py1, px2, py2, ap, gx1, gy1, gx2, gy2, ag);
        const float s = pd_scores[((size_t)b * NA + a) * NC + label];
        const float i2 = iou * iou;
        sm[a] = sigmoid_f(s) * (i2 * i2 * i2);
    }
    __syncthreads();

    // 13 sequential argmax passes; tie-break: lower index wins (matches lax.top_k)
    for (int k = 0; k < NK; ++k) {
        float bv = -3.0f;
        int   bi = 0x7fffffff;
        for (int a = tid; a < NA; a += 256) {
            const float v = sm[a];
            if (v > bv || (v == bv && a < bi)) { bv = v; bi = a; }
        }
        #pragma unroll
        for (int off = 32; off; off >>= 1) {
            const float ov = __shfl_xor(bv, off);
            const int   oi = __shfl_xor(bi, off);
            if (ov > bv || (ov == bv && oi < bi)) { bv = ov; bi = oi; }
        }
        const int wave = tid >> 6;
        if ((tid & 63) == 0) { wv[wave] = bv; wi[wave] = bi; }
        __syncthreads();
        if (tid == 0) {
            #pragma unroll
            for (int w = 1; w < 4; ++w) {
                if (wv[w] > bv || (wv[w] == bv && wi[w] < bi)) { bv = wv[w]; bi = wi[w]; }
            }
            out[k] = bi;
            sm[bi] = -2.0f;   // exclude from subsequent passes (all valid metrics >= 0)
        }
        __syncthreads();
    }
}

// ---------------- Kernel 2: per-anchor assignment + outputs ----------------
__global__ __launch_bounds__(256) void assign_kernel(
    const float* __restrict__ pd_scores,
    const float* __restrict__ pd_bboxes,
    const int* __restrict__ gt_labels,
    const float* __restrict__ gt_bboxes,
    const int* __restrict__ mask_gt,       // bool uploaded as int32
    const int* __restrict__ topk_idx,
    float* __restrict__ out)
{
    const int b = blockIdx.y;
    const int a0 = blockIdx.x * 256;
    const int tid = threadIdx.x;

    __shared__ float s_gx1[NG], s_gy1[NG], s_gx2[NG], s_gy2[NG], s_gar[NG];
    __shared__ float s_graw[NG][4];
    __shared__ int   s_lab[NG];
    __shared__ int   s_val[NG];
    __shared__ int   s_tk[NG][NK];
    __shared__ int   s_albl[256];
    __shared__ float s_aiou[256];

    if (tid < NG) {
        const float4 gb = *reinterpret_cast<const float4*>(gt_bboxes + ((size_t)b * NG + tid) * 4);
        s_graw[tid][0] = gb.x; s_graw[tid][1] = gb.y; s_graw[tid][2] = gb.z; s_graw[tid][3] = gb.w;
        const float gx1 = gb.x - gb.z * 0.5f, gy1 = gb.y - gb.w * 0.5f;
        const float gx2 = gb.x + gb.z * 0.5f, gy2 = gb.y + gb.w * 0.5f;
        s_gx1[tid] = gx1; s_gy1[tid] = gy1; s_gx2[tid] = gx2; s_gy2[tid] = gy2;
        s_gar[tid] = (gx2 - gx1) * (gy2 - gy1);
        s_lab[tid] = gt_labels[b * NG + tid];
        s_val[tid] = mask_gt[b * NG + tid];
    }
    for (int i = tid; i < NG * NK; i += 256) {
        s_tk[i / NK][i % NK] = topk_idx[(size_t)b * NG * NK + i];
    }
    __syncthreads();

    const int a = a0 + tid;
    const bool active = a < NA;

    float anchor_max = -1.0f;              // invalid-gt sentinel value in reference
    unsigned long long cand = 0ull;
    float px1 = 0, py1 = 0, px2 = 0, py2 = 0, ap = 0;
    const float* srow = pd_scores + ((size_t)b * NA + a) * NC;

    if (active) {
        const float4 pb = *reinterpret_cast<const float4*>(pd_bboxes + ((size_t)b * NA + a) * 4);
        px1 = pb.x - pb.z * 0.5f; py1 = pb.y - pb.w * 0.5f;
        px2 = pb.x + pb.z * 0.5f; py2 = pb.y + pb.w * 0.5f;
        ap = (px2 - px1) * (py2 - py1);
        for (int g = 0; g < NG; ++g) {
            if (!s_val[g]) continue;
            const float iou = iou_from_corners(px1, py1, px2, py2, ap,
                                               s_gx1[g], s_gy1[g], s_gx2[g], s_gy2[g], s_gar[g]);
            const float s = srow[s_lab[g]];
            const float i2 = iou * iou;
            const float m = sigmoid_f(s) * (i2 * i2 * i2);
            anchor_max = fmaxf(anchor_max, m);
            bool c = false;
            #pragma unroll
            for (int k = 0; k < NK; ++k) c = c || (s_tk[g][k] == a);
            if (c) cand |= (1ull << g);
        }
    }

    const bool fg = (cand != 0ull);
    int assigned = 0;
    float aiou = 0.0f;
    if (fg) {
        const int first = __ffsll((unsigned long long)cand) - 1;
        int last = -1;
        unsigned long long rem = cand;
        while (rem) {
            const int g = __ffsll((unsigned long long)rem) - 1;
            rem &= rem - 1;
            const float iou = iou_from_corners(px1, py1, px2, py2, ap,
                                               s_gx1[g], s_gy1[g], s_gx2[g], s_gy2[g], s_gar[g]);
            const float s = srow[s_lab[g]];
            const float i2 = iou * iou;
            const float m = sigmoid_f(s) * (i2 * i2 * i2);
            if (m >= anchor_max) last = g;   // keep LAST g meeting the max (reference last_max)
        }
        assigned = (last >= 0) ? last : first;
        aiou = iou_from_corners(px1, py1, px2, py2, ap,
                                s_gx1[assigned], s_gy1[assigned], s_gx2[assigned], s_gy2[assigned],
                                s_gar[assigned]);
    }

    s_albl[tid] = fg ? s_lab[assigned] : -1;   // -1: matches no class -> zero rows
    s_aiou[tid] = fg ? aiou : 0.0f;

    if (active) {
        float4 ob;
        if (fg) ob = make_float4(s_graw[assigned][0], s_graw[assigned][1],
                                 s_graw[assigned][2], s_graw[assigned][3]);
        else    ob = make_float4(0.f, 0.f, 0.f, 0.f);
        *reinterpret_cast<float4*>(out + OFF_BBOX + ((size_t)b * NA + a) * 4) = ob;
        out[OFF_FG + (size_t)b * NA + a] = fg ? 1.0f : 0.0f;
    }
    __syncthreads();

    const int cnt = min(256, NA - a0);
    for (int i = tid; i < cnt * NC; i += 256) {
        const int al = i / NC;
        const int c  = i - al * NC;
        const int lbl = s_albl[al];
        const float lv = (c == lbl) ? 1.0f : 0.0f;
        const float sv = (c == lbl) ? s_aiou[al] : 0.0f;
        const size_t base = ((size_t)b * NA + (a0 + al)) * NC + c;
        out[OFF_LBL + base] = lv;
        out[OFF_SCR + base] = sv;
    }
}

extern "C" void kernel_launch(void* const* d_in, const int* in_sizes, int n_in,
                              void* d_out, int out_size, void* d_ws, size_t ws_size,
                              hipStream_t stream) {
    const float* pd_scores = (const float*)d_in[0];
    const float* pd_bboxes = (const float*)d_in[1];
    // d_in[2] = anc_points (unused by reference math)
    const int*   gt_labels = (const int*)d_in[3];
    const float* gt_bboxes = (const float*)d_in[4];
    const int*   mask_gt   = (const int*)d_in[5];   // bool -> int32 on upload
    float* out = (float*)d_out;
    int* topk = (int*)d_ws;   // B*G*K ints = 106 KB

    dim3 g1(NG, NB);
    topk_kernel<<<g1, 256, 0, stream>>>(pd_scores, pd_bboxes, gt_labels, gt_bboxes, mask_gt, topk);

    dim3 g2((NA + 255) / 256, NB);
    assign_kernel<<<g2, 256, 0, stream>>>(pd_scores, pd_bboxes, gt_labels, gt_bboxes, mask_gt, topk, out);
}

// Round 3
// 402.272 us; speedup vs baseline: 1.4583x; 1.4583x over previous
//
#include <hip/hip_runtime.h>

#define NB 32
#define NA 8400
#define NG 64
#define NC 80
#define NK 13
#define TILE0 64
#define NT0 132          // ceil(8400/64)

// output offsets (floats) in d_out
#define OFF_LBL  0
#define OFF_BBOX 21504000
#define OFF_SCR  22579200
#define OFF_FG   44083200

// ws layout (bytes)
#define WS_METRICS_OFF 0
#define WS_METRICS_SZ  (32ull*64*8400*4)          // 68,812,800
#define WS_MASK_OFF    WS_METRICS_SZ
#define WS_MASK_SZ     (32ull*8400*8)             // 2,150,400
#define WS_NEEDED      (WS_METRICS_SZ + WS_MASK_SZ)

__device__ __forceinline__ float sigmoid_f(float x) {
    return 1.0f / (1.0f + expf(-x));
}

__device__ __forceinline__ float iou_corners(
    float px1, float py1, float px2, float py2, float ap,
    float gx1, float gy1, float gx2, float gy2, float ag)
{
    float ix1 = fmaxf(px1, gx1), iy1 = fmaxf(py1, gy1);
    float ix2 = fminf(px2, gx2), iy2 = fminf(py2, gy2);
    float inter = fmaxf(ix2 - ix1, 0.0f) * fmaxf(iy2 - iy1, 0.0f);
    return inter / (ap + ag - inter + 1e-7f);
}

// ============ K0: metrics[b][g][a], coalesced score read, one pass ============
__global__ __launch_bounds__(256) void metrics_kernel(
    const float* __restrict__ pd_scores,   // [B,A,C]
    const float* __restrict__ pd_bboxes,   // [B,A,4]
    const int* __restrict__ gt_labels,     // [B,G]
    const float* __restrict__ gt_bboxes,   // [B,G,4]
    const int* __restrict__ mask_gt,       // [B,G] (bool as int32)
    float* __restrict__ metrics)           // [B,G,A]
{
    const int b  = blockIdx.y;
    const int a0 = blockIdx.x * TILE0;
    const int tid = threadIdx.x;
    const int an = min(TILE0, NA - a0);

    __shared__ float s_sc[TILE0 * 81];   // sigmoid(scores), pad 81 (17 mod 32, conflict-free)
    __shared__ float s_pb[TILE0 * 5];    // px1,py1,px2,py2,area
    __shared__ float s_gb[NG * 5];
    __shared__ int   s_lab[NG];
    __shared__ int   s_val[NG];

    // scores for this tile are contiguous: [an*80] floats
    const float* sbase = pd_scores + ((size_t)b * NA + a0) * NC;
    for (int i4 = tid; i4 < an * 20; i4 += 256) {
        const float4 v = reinterpret_cast<const float4*>(sbase)[i4];
        const int al = i4 / 20;
        const int c  = (i4 % 20) * 4;
        float* d = &s_sc[al * 81 + c];
        d[0] = sigmoid_f(v.x); d[1] = sigmoid_f(v.y);
        d[2] = sigmoid_f(v.z); d[3] = sigmoid_f(v.w);
    }
    if (tid < an) {
        const float4 pb = *reinterpret_cast<const float4*>(pd_bboxes + ((size_t)b * NA + a0 + tid) * 4);
        const float px1 = pb.x - pb.z * 0.5f, py1 = pb.y - pb.w * 0.5f;
        const float px2 = pb.x + pb.z * 0.5f, py2 = pb.y + pb.w * 0.5f;
        s_pb[tid * 5 + 0] = px1; s_pb[tid * 5 + 1] = py1;
        s_pb[tid * 5 + 2] = px2; s_pb[tid * 5 + 3] = py2;
        s_pb[tid * 5 + 4] = (px2 - px1) * (py2 - py1);
    }
    if (tid >= 64 && tid < 64 + NG) {
        const int g = tid - 64;
        const float4 gb = *reinterpret_cast<const float4*>(gt_bboxes + ((size_t)b * NG + g) * 4);
        const float gx1 = gb.x - gb.z * 0.5f, gy1 = gb.y - gb.w * 0.5f;
        const float gx2 = gb.x + gb.z * 0.5f, gy2 = gb.y + gb.w * 0.5f;
        s_gb[g * 5 + 0] = gx1; s_gb[g * 5 + 1] = gy1;
        s_gb[g * 5 + 2] = gx2; s_gb[g * 5 + 3] = gy2;
        s_gb[g * 5 + 4] = (gx2 - gx1) * (gy2 - gy1);
        s_lab[g] = gt_labels[b * NG + g];
        s_val[g] = mask_gt[b * NG + g];
    }
    __syncthreads();

    const int a_local = tid & 63;
    const int ggrp    = tid >> 6;
    if (a_local < an) {
        const float px1 = s_pb[a_local * 5 + 0], py1 = s_pb[a_local * 5 + 1];
        const float px2 = s_pb[a_local * 5 + 2], py2 = s_pb[a_local * 5 + 3];
        const float ap  = s_pb[a_local * 5 + 4];
        #pragma unroll 4
        for (int gg = 0; gg < 16; ++gg) {
            const int g = gg * 4 + ggrp;      // each wave owns one g per iter -> 256B wave store
            float m = -1.0f;
            if (s_val[g]) {
                const float iou = iou_corners(px1, py1, px2, py2, ap,
                                              s_gb[g*5+0], s_gb[g*5+1], s_gb[g*5+2], s_gb[g*5+3], s_gb[g*5+4]);
                const float i2 = iou * iou;
                m = s_sc[a_local * 81 + s_lab[g]] * (i2 * i2 * i2);
            }
            metrics[((size_t)(b * NG + g)) * NA + a0 + a_local] = m;
        }
    }
}

// ============ K1: per-(b,g) top-13 -> scatter into cand_mask bits ============
__global__ __launch_bounds__(256) void topk_kernel(
    const float* __restrict__ metrics,      // [B,G,A]
    const int* __restrict__ mask_gt,
    unsigned long long* __restrict__ cand_mask)  // [B,A]
{
    const int g = blockIdx.x;
    const int b = blockIdx.y;
    const int tid = threadIdx.x;

    if (mask_gt[b * NG + g] == 0) return;   // block-uniform exit; contributes no bits

    __shared__ float sm[NA];
    __shared__ float wv[4];
    __shared__ int   wi[4];
    __shared__ int   s_sel[NK];

    const float* mrow = metrics + (size_t)(b * NG + g) * NA;
    for (int a = tid; a < NA; a += 256) sm[a] = mrow[a];
    __syncthreads();

    for (int k = 0; k < NK; ++k) {
        float bv = -3.0f;
        int   bi = 0x7fffffff;
        for (int a = tid; a < NA; a += 256) {
            const float v = sm[a];
            if (v > bv || (v == bv && a < bi)) { bv = v; bi = a; }
        }
        #pragma unroll
        for (int off = 32; off; off >>= 1) {
            const float ov = __shfl_xor(bv, off);
            const int   oi = __shfl_xor(bi, off);
            if (ov > bv || (ov == bv && oi < bi)) { bv = ov; bi = oi; }
        }
        const int wave = tid >> 6;
        if ((tid & 63) == 0) { wv[wave] = bv; wi[wave] = bi; }
        __syncthreads();
        if (tid == 0) {
            #pragma unroll
            for (int w = 1; w < 4; ++w) {
                if (wv[w] > bv || (wv[w] == bv && wi[w] < bi)) { bv = wv[w]; bi = wi[w]; }
            }
            s_sel[k] = bi;
            sm[bi] = -2.0f;
        }
        __syncthreads();
    }
    if (tid < NK) {
        atomicOr(&cand_mask[(size_t)b * NA + s_sel[tid]], 1ull << g);
    }
}

// ============ K2: per-anchor resolve + outputs (no score gather) ============
__global__ __launch_bounds__(256) void assign_kernel(
    const float* __restrict__ metrics,
    const float* __restrict__ pd_bboxes,
    const int* __restrict__ gt_labels,
    const float* __restrict__ gt_bboxes,
    const unsigned long long* __restrict__ cand_mask,
    float* __restrict__ out)
{
    const int b = blockIdx.y;
    const int a0 = blockIdx.x * 256;
    const int tid = threadIdx.x;
    const int a = a0 + tid;
    const bool active = a < NA;

    __shared__ float s_gb[NG * 5];
    __shared__ float s_graw[NG][4];
    __shared__ int   s_lab[NG];
    __shared__ int   s_albl[256];
    __shared__ float s_aiou[256];

    if (tid < NG) {
        const float4 gb = *reinterpret_cast<const float4*>(gt_bboxes + ((size_t)b * NG + tid) * 4);
        s_graw[tid][0] = gb.x; s_graw[tid][1] = gb.y; s_graw[tid][2] = gb.z; s_graw[tid][3] = gb.w;
        const float gx1 = gb.x - gb.z * 0.5f, gy1 = gb.y - gb.w * 0.5f;
        const float gx2 = gb.x + gb.z * 0.5f, gy2 = gb.y + gb.w * 0.5f;
        s_gb[tid * 5 + 0] = gx1; s_gb[tid * 5 + 1] = gy1;
        s_gb[tid * 5 + 2] = gx2; s_gb[tid * 5 + 3] = gy2;
        s_gb[tid * 5 + 4] = (gx2 - gx1) * (gy2 - gy1);
        s_lab[tid] = gt_labels[b * NG + tid];
    }
    __syncthreads();

    unsigned long long cand = 0ull;
    float maxv = -2.0f;
    int   last = -1;
    if (active) {
        cand = cand_mask[(size_t)b * NA + a];
        const float* mcol = metrics + (size_t)b * NG * NA + a;
        for (int g = 0; g < NG; ++g) {
            const float mv = mcol[(size_t)g * NA];        // coalesced across threads
            const bool cb = (cand >> g) & 1ull;
            if (mv > maxv)       { maxv = mv; last = cb ? g : -1; }
            else if (mv == maxv && cb) { last = g; }
        }
    }

    const bool fg = (cand != 0ull);
    int assigned = 0;
    float aiou = 0.0f;
    if (fg) {
        assigned = (last >= 0) ? last : (__ffsll(cand) - 1);
        const float4 pb = *reinterpret_cast<const float4*>(pd_bboxes + ((size_t)b * NA + a) * 4);
        const float px1 = pb.x - pb.z * 0.5f, py1 = pb.y - pb.w * 0.5f;
        const float px2 = pb.x + pb.z * 0.5f, py2 = pb.y + pb.w * 0.5f;
        const float ap = (px2 - px1) * (py2 - py1);
        aiou = iou_corners(px1, py1, px2, py2, ap,
                           s_gb[assigned*5+0], s_gb[assigned*5+1],
                           s_gb[assigned*5+2], s_gb[assigned*5+3], s_gb[assigned*5+4]);
    }

    s_albl[tid] = fg ? s_lab[assigned] : -1;
    s_aiou[tid] = fg ? aiou : 0.0f;

    if (active) {
        float4 ob = fg ? make_float4(s_graw[assigned][0], s_graw[assigned][1],
                                     s_graw[assigned][2], s_graw[assigned][3])
                       : make_float4(0.f, 0.f, 0.f, 0.f);
        *reinterpret_cast<float4*>(out + OFF_BBOX + ((size_t)b * NA + a) * 4) = ob;
        out[OFF_FG + (size_t)b * NA + a] = fg ? 1.0f : 0.0f;
    }
    __syncthreads();

    const int cnt = min(256, NA - a0);
    for (int i = tid; i < cnt * NC; i += 256) {
        const int al = i / NC;
        const int c  = i - al * NC;
        const int lbl = s_albl[al];
        const float lv = (c == lbl) ? 1.0f : 0.0f;
        const float sv = (c == lbl) ? s_aiou[al] : 0.0f;
        const size_t base = ((size_t)b * NA + (a0 + al)) * NC + c;
        out[OFF_LBL + base] = lv;
        out[OFF_SCR + base] = sv;
    }
}

// ================= fallback (round-2 verified path, 106 KB ws) =================
__global__ __launch_bounds__(256) void topk_fb(
    const float* __restrict__ pd_scores, const float* __restrict__ pd_bboxes,
    const int* __restrict__ gt_labels, const float* __restrict__ gt_bboxes,
    const int* __restrict__ mask_gt, int* __restrict__ topk_idx)
{
    const int g = blockIdx.x, b = blockIdx.y, tid = threadIdx.x;
    int* outp = topk_idx + (b * NG + g) * NK;
    if (mask_gt[b * NG + g] == 0) { if (tid < NK) outp[tid] = -1; return; }
    __shared__ float sm[NA];
    __shared__ float wv[4]; __shared__ int wi[4];
    const int label = gt_labels[b * NG + g];
    const float4 gb = *reinterpret_cast<const float4*>(gt_bboxes + (size_t)(b * NG + g) * 4);
    const float gx1 = gb.x - gb.z * 0.5f, gy1 = gb.y - gb.w * 0.5f;
    const float gx2 = gb.x + gb.z * 0.5f, gy2 = gb.y + gb.w * 0.5f;
    const float ag = (gx2 - gx1) * (gy2 - gy1);
    for (int a = tid; a < NA; a += 256) {
        const float4 pb = *reinterpret_cast<const float4*>(pd_bboxes + ((size_t)b * NA + a) * 4);
        const float px1 = pb.x - pb.z * 0.5f, py1 = pb.y - pb.w * 0.5f;
        const float px2 = pb.x + pb.z * 0.5f, py2 = pb.y + pb.w * 0.5f;
        const float ap = (px2 - px1) * (py2 - py1);
        const float iou = iou_corners(px1, py1, px2, py2, ap, gx1, gy1, gx2, gy2, ag);
        const float s = pd_scores[((size_t)b * NA + a) * NC + label];
        const float i2 = iou * iou;
        sm[a] = sigmoid_f(s) * (i2 * i2 * i2);
    }
    __syncthreads();
    for (int k = 0; k < NK; ++k) {
        float bv = -3.0f; int bi = 0x7fffffff;
        for (int a = tid; a < NA; a += 256) {
            const float v = sm[a];
            if (v > bv || (v == bv && a < bi)) { bv = v; bi = a; }
        }
        #pragma unroll
        for (int off = 32; off; off >>= 1) {
            const float ov = __shfl_xor(bv, off); const int oi = __shfl_xor(bi, off);
            if (ov > bv || (ov == bv && oi < bi)) { bv = ov; bi = oi; }
        }
        if ((tid & 63) == 0) { wv[tid >> 6] = bv; wi[tid >> 6] = bi; }
        __syncthreads();
        if (tid == 0) {
            #pragma unroll
            for (int w = 1; w < 4; ++w)
                if (wv[w] > bv || (wv[w] == bv && wi[w] < bi)) { bv = wv[w]; bi = wi[w]; }
            outp[k] = bi; sm[bi] = -2.0f;
        }
        __syncthreads();
    }
}

__global__ __launch_bounds__(256) void assign_fb(
    const float* __restrict__ pd_scores, const float* __restrict__ pd_bboxes,
    const int* __restrict__ gt_labels, const float* __restrict__ gt_bboxes,
    const int* __restrict__ mask_gt, const int* __restrict__ topk_idx,
    float* __restrict__ out)
{
    const int b = blockIdx.y, a0 = blockIdx.x * 256, tid = threadIdx.x;
    __shared__ float s_gx1[NG], s_gy1[NG], s_gx2[NG], s_gy2[NG], s_gar[NG];
    __shared__ float s_graw[NG][4];
    __shared__ int s_lab[NG], s_val[NG], s_tk[NG][NK], s_albl[256];
    __shared__ float s_aiou[256];
    if (tid < NG) {
        const float4 gb = *reinterpret_cast<const float4*>(gt_bboxes + ((size_t)b * NG + tid) * 4);
        s_graw[tid][0] = gb.x; s_graw[tid][1] = gb.y; s_graw[tid][2] = gb.z; s_graw[tid][3] = gb.w;
        const float gx1 = gb.x - gb.z * 0.5f, gy1 = gb.y - gb.w * 0.5f;
        const float gx2 = gb.x + gb.z * 0.5f, gy2 = gb.y + gb.w * 0.5f;
        s_gx1[tid] = gx1; s_gy1[tid] = gy1; s_gx2[tid] = gx2; s_gy2[tid] = gy2;
        s_gar[tid] = (gx2 - gx1) * (gy2 - gy1);
        s_lab[tid] = gt_labels[b * NG + tid];
        s_val[tid] = mask_gt[b * NG + tid];
    }
    for (int i = tid; i < NG * NK; i += 256) s_tk[i / NK][i % NK] = topk_idx[(size_t)b * NG * NK + i];
    __syncthreads();
    const int a = a0 + tid;
    const bool active = a < NA;
    float anchor_max = -1.0f;
    unsigned long long cand = 0ull;
    float px1 = 0, py1 = 0, px2 = 0, py2 = 0, ap = 0;
    const float* srow = pd_scores + ((size_t)b * NA + a) * NC;
    if (active) {
        const float4 pb = *reinterpret_cast<const float4*>(pd_bboxes + ((size_t)b * NA + a) * 4);
        px1 = pb.x - pb.z * 0.5f; py1 = pb.y - pb.w * 0.5f;
        px2 = pb.x + pb.z * 0.5f; py2 = pb.y + pb.w * 0.5f;
        ap = (px2 - px1) * (py2 - py1);
        for (int g = 0; g < NG; ++g) {
            if (!s_val[g]) continue;
            const float iou = iou_corners(px1, py1, px2, py2, ap, s_gx1[g], s_gy1[g], s_gx2[g], s_gy2[g], s_gar[g]);
            const float i2 = iou * iou;
            const float m = sigmoid_f(srow[s_lab[g]]) * (i2 * i2 * i2);
            anchor_max = fmaxf(anchor_max, m);
            bool c = false;
            #pragma unroll
            for (int k = 0; k < NK; ++k) c = c || (s_tk[g][k] == a);
            if (c) cand |= (1ull << g);
        }
    }
    const bool fg = (cand != 0ull);
    int assigned = 0; float aiou = 0.0f;
    if (fg) {
        const int first = __ffsll(cand) - 1;
        int lastg = -1;
        unsigned long long rem = cand;
        while (rem) {
            const int g = __ffsll(rem) - 1; rem &= rem - 1;
            const float iou = iou_corners(px1, py1, px2, py2, ap, s_gx1[g], s_gy1[g], s_gx2[g], s_gy2[g], s_gar[g]);
            const float i2 = iou * iou;
            const float m = sigmoid_f(srow[s_lab[g]]) * (i2 * i2 * i2);
            if (m >= anchor_max) lastg = g;
        }
        assigned = (lastg >= 0) ? lastg : first;
        aiou = iou_corners(px1, py1, px2, py2, ap, s_gx1[assigned], s_gy1[assigned], s_gx2[assigned], s_gy2[assigned], s_gar[assigned]);
    }
    s_albl[tid] = fg ? s_lab[assigned] : -1;
    s_aiou[tid] = fg ? aiou : 0.0f;
    if (active) {
        float4 ob = fg ? make_float4(s_graw[assigned][0], s_graw[assigned][1], s_graw[assigned][2], s_graw[assigned][3])
                       : make_float4(0.f, 0.f, 0.f, 0.f);
        *reinterpret_cast<float4*>(out + OFF_BBOX + ((size_t)b * NA + a) * 4) = ob;
        out[OFF_FG + (size_t)b * NA + a] = fg ? 1.0f : 0.0f;
    }
    __syncthreads();
    const int cnt = min(256, NA - a0);
    for (int i = tid; i < cnt * NC; i += 256) {
        const int al = i / NC, c = i - al * NC;
        const int lbl = s_albl[al];
        const size_t base = ((size_t)b * NA + (a0 + al)) * NC + c;
        out[OFF_LBL + base] = (c == lbl) ? 1.0f : 0.0f;
        out[OFF_SCR + base] = (c == lbl) ? s_aiou[al] : 0.0f;
    }
}

extern "C" void kernel_launch(void* const* d_in, const int* in_sizes, int n_in,
                              void* d_out, int out_size, void* d_ws, size_t ws_size,
                              hipStream_t stream) {
    const float* pd_scores = (const float*)d_in[0];
    const float* pd_bboxes = (const float*)d_in[1];
    const int*   gt_labels = (const int*)d_in[3];
    const float* gt_bboxes = (const float*)d_in[4];
    const int*   mask_gt   = (const int*)d_in[5];
    float* out = (float*)d_out;

    if (ws_size >= WS_NEEDED) {
        float* metrics = (float*)((char*)d_ws + WS_METRICS_OFF);
        unsigned long long* cmask = (unsigned long long*)((char*)d_ws + WS_MASK_OFF);

        hipMemsetAsync(cmask, 0, WS_MASK_SZ, stream);

        dim3 g0(NT0, NB);
        metrics_kernel<<<g0, 256, 0, stream>>>(pd_scores, pd_bboxes, gt_labels, gt_bboxes, mask_gt, metrics);

        dim3 g1(NG, NB);
        topk_kernel<<<g1, 256, 0, stream>>>(metrics, mask_gt, cmask);

        dim3 g2((NA + 255) / 256, NB);
        assign_kernel<<<g2, 256, 0, stream>>>(metrics, pd_bboxes, gt_labels, gt_bboxes, cmask, out);
    } else {
        int* topk = (int*)d_ws;
        dim3 g1(NG, NB);
        topk_fb<<<g1, 256, 0, stream>>>(pd_scores, pd_bboxes, gt_labels, gt_bboxes, mask_gt, topk);
        dim3 g2((NA + 255) / 256, NB);
        assign_fb<<<g2, 256, 0, stream>>>(pd_scores, pd_bboxes, gt_labels, gt_bboxes, mask_gt, topk, out);
    }
}

// Round 4
// 367.768 us; speedup vs baseline: 1.5951x; 1.0938x over previous
//
#include <hip/hip_runtime.h>

#define NB 32
#define NA 8400
#define NG 64
#define NC 80
#define NK 13
#define TILE0 64
#define NT0 132          // ceil(8400/64)

// output offsets (floats) in d_out
#define OFF_LBL  0
#define OFF_BBOX 21504000
#define OFF_SCR  22579200
#define OFF_FG   44083200

// ws layout (bytes)
#define WS_METRICS_SZ  (32ull*64*8400*4)          // 68,812,800
#define WS_MASK_SZ     (32ull*8400*8)             // 2,150,400
#define WS_AMAX_SZ     (32ull*8400*4)             // 1,075,200
#define WS_NEEDED      (WS_METRICS_SZ + WS_MASK_SZ + WS_AMAX_SZ)

__device__ __forceinline__ float sigmoid_f(float x) {
    return 1.0f / (1.0f + expf(-x));
}

__device__ __forceinline__ float iou_corners(
    float px1, float py1, float px2, float py2, float ap,
    float gx1, float gy1, float gx2, float gy2, float ag)
{
    float ix1 = fmaxf(px1, gx1), iy1 = fmaxf(py1, gy1);
    float ix2 = fminf(px2, gx2), iy2 = fminf(py2, gy2);
    float inter = fmaxf(ix2 - ix1, 0.0f) * fmaxf(iy2 - iy1, 0.0f);
    return inter / (ap + ag - inter + 1e-7f);
}

// ==== K0: metrics[b][g][a] + per-anchor max + cand_mask zeroing ====
__global__ __launch_bounds__(256) void metrics_kernel(
    const float* __restrict__ pd_scores,   // [B,A,C]
    const float* __restrict__ pd_bboxes,   // [B,A,4]
    const int* __restrict__ gt_labels,     // [B,G]
    const float* __restrict__ gt_bboxes,   // [B,G,4]
    const int* __restrict__ mask_gt,       // [B,G] (bool as int32)
    float* __restrict__ metrics,           // [B,G,A]
    float* __restrict__ amax_arr,          // [B,A]
    unsigned long long* __restrict__ cmask)// [B,A] (zeroed here)
{
    const int b  = blockIdx.y;
    const int a0 = blockIdx.x * TILE0;
    const int tid = threadIdx.x;
    const int an = min(TILE0, NA - a0);

    __shared__ float s_sc[TILE0 * 81];   // sigmoid(scores), pad 81 -> conflict-free
    __shared__ float s_pb[TILE0 * 5];    // px1,py1,px2,py2,area
    __shared__ float s_gb[NG * 5];
    __shared__ float s_pm[4][TILE0];     // per-wave partial anchor max
    __shared__ int   s_lab[NG];
    __shared__ int   s_val[NG];

    const float* sbase = pd_scores + ((size_t)b * NA + a0) * NC;
    for (int i4 = tid; i4 < an * 20; i4 += 256) {
        const float4 v = reinterpret_cast<const float4*>(sbase)[i4];
        const int al = i4 / 20;
        const int c  = (i4 % 20) * 4;
        float* d = &s_sc[al * 81 + c];
        d[0] = sigmoid_f(v.x); d[1] = sigmoid_f(v.y);
        d[2] = sigmoid_f(v.z); d[3] = sigmoid_f(v.w);
    }
    if (tid < an) {
        const float4 pb = *reinterpret_cast<const float4*>(pd_bboxes + ((size_t)b * NA + a0 + tid) * 4);
        const float px1 = pb.x - pb.z * 0.5f, py1 = pb.y - pb.w * 0.5f;
        const float px2 = pb.x + pb.z * 0.5f, py2 = pb.y + pb.w * 0.5f;
        s_pb[tid * 5 + 0] = px1; s_pb[tid * 5 + 1] = py1;
        s_pb[tid * 5 + 2] = px2; s_pb[tid * 5 + 3] = py2;
        s_pb[tid * 5 + 4] = (px2 - px1) * (py2 - py1);
    }
    if (tid >= 64 && tid < 64 + NG) {
        const int g = tid - 64;
        const float4 gb = *reinterpret_cast<const float4*>(gt_bboxes + ((size_t)b * NG + g) * 4);
        const float gx1 = gb.x - gb.z * 0.5f, gy1 = gb.y - gb.w * 0.5f;
        const float gx2 = gb.x + gb.z * 0.5f, gy2 = gb.y + gb.w * 0.5f;
        s_gb[g * 5 + 0] = gx1; s_gb[g * 5 + 1] = gy1;
        s_gb[g * 5 + 2] = gx2; s_gb[g * 5 + 3] = gy2;
        s_gb[g * 5 + 4] = (gx2 - gx1) * (gy2 - gy1);
        s_lab[g] = gt_labels[b * NG + g];
        s_val[g] = mask_gt[b * NG + g];
    }
    __syncthreads();

    const int a_local = tid & 63;
    const int ggrp    = tid >> 6;
    float pm = -1.0f;
    if (a_local < an) {
        const float px1 = s_pb[a_local * 5 + 0], py1 = s_pb[a_local * 5 + 1];
        const float px2 = s_pb[a_local * 5 + 2], py2 = s_pb[a_local * 5 + 3];
        const float ap  = s_pb[a_local * 5 + 4];
        #pragma unroll 4
        for (int gg = 0; gg < 16; ++gg) {
            const int g = gg * 4 + ggrp;
            float m = -1.0f;
            if (s_val[g]) {
                const float iou = iou_corners(px1, py1, px2, py2, ap,
                                              s_gb[g*5+0], s_gb[g*5+1], s_gb[g*5+2], s_gb[g*5+3], s_gb[g*5+4]);
                const float i2 = iou * iou;
                m = s_sc[a_local * 81 + s_lab[g]] * (i2 * i2 * i2);
            }
            pm = fmaxf(pm, m);
            metrics[((size_t)(b * NG + g)) * NA + a0 + a_local] = m;
        }
    }
    s_pm[ggrp][a_local] = pm;
    __syncthreads();
    if (tid < an) {
        const float am = fmaxf(fmaxf(s_pm[0][tid], s_pm[1][tid]),
                               fmaxf(s_pm[2][tid], s_pm[3][tid]));
        amax_arr[(size_t)b * NA + a0 + tid] = am;
        cmask[(size_t)b * NA + a0 + tid] = 0ull;
    }
}

// ==== K1: per-(b,g) top-13 via register lists + tournament ====
__global__ __launch_bounds__(256) void topk_kernel(
    const float* __restrict__ metrics,      // [B,G,A]
    const int* __restrict__ mask_gt,
    unsigned long long* __restrict__ cand_mask)  // [B,A]
{
    const int g = blockIdx.x;
    const int b = blockIdx.y;
    const int tid = threadIdx.x;

    if (mask_gt[b * NG + g] == 0) return;   // block-uniform exit before any barrier

    const float* __restrict__ mrow = metrics + (size_t)(b * NG + g) * NA;

    // per-thread top-13 sorted register list (static indexing only)
    float v[NK]; int ix[NK];
    #pragma unroll
    for (int k = 0; k < NK; ++k) { v[k] = -3.0f; ix[k] = 0x7fffffff; }

    for (int base = tid * 4; base < NA; base += 1024) {   // NA % 4 == 0 -> full float4
        const float4 m4 = *reinterpret_cast<const float4*>(mrow + base);
        const float mv4[4] = {m4.x, m4.y, m4.z, m4.w};
        #pragma unroll
        for (int j = 0; j < 4; ++j) {
            float m = mv4[j];
            int   a = base + j;
            // strict > : within a thread indices only increase, so ties keep the
            // earlier (lower-index) entry -> matches lax.top_k stability
            if (m > v[NK-1]) {
                #pragma unroll
                for (int k = 0; k < NK; ++k) {
                    if (m > v[k]) {
                        const float tv = v[k]; v[k] = m;  m = tv;
                        const int   ti = ix[k]; ix[k] = a; a = ti;
                    }
                }
            }
        }
    }

    __shared__ float s_wv[4];
    __shared__ int   s_wi[4];
    __shared__ int   s_sel[NK];

    // 13-round tournament over thread heads; tie -> lower anchor index
    for (int r = 0; r < NK; ++r) {
        float bv = v[0]; int bi = ix[0];
        #pragma unroll
        for (int off = 32; off; off >>= 1) {
            const float ov = __shfl_xor(bv, off);
            const int   oi = __shfl_xor(bi, off);
            if (ov > bv || (ov == bv && oi < bi)) { bv = ov; bi = oi; }
        }
        if ((tid & 63) == 0) { s_wv[tid >> 6] = bv; s_wi[tid >> 6] = bi; }
        __syncthreads();
        bv = s_wv[0]; bi = s_wi[0];
        #pragma unroll
        for (int w = 1; w < 4; ++w) {
            if (s_wv[w] > bv || (s_wv[w] == bv && s_wi[w] < bi)) { bv = s_wv[w]; bi = s_wi[w]; }
        }
        if (tid == 0) s_sel[r] = bi;
        if (v[0] == bv && ix[0] == bi) {      // unique anchor -> exactly one popper
            #pragma unroll
            for (int k = 0; k < NK - 1; ++k) { v[k] = v[k+1]; ix[k] = ix[k+1]; }
            v[NK-1] = -3.0f; ix[NK-1] = 0x7fffffff;
        }
        __syncthreads();
    }

    if (tid < NK) {
        atomicOr(&cand_mask[(size_t)b * NA + s_sel[tid]], 1ull << g);
    }
}

// ==== K2: per-anchor resolve + outputs (sparse metric reads only) ====
__global__ __launch_bounds__(256) void assign_kernel(
    const float* __restrict__ metrics,
    const float* __restrict__ amax_arr,
    const float* __restrict__ pd_bboxes,
    const int* __restrict__ gt_labels,
    const float* __restrict__ gt_bboxes,
    const unsigned long long* __restrict__ cand_mask,
    float* __restrict__ out)
{
    const int b = blockIdx.y;
    const int a0 = blockIdx.x * 256;
    const int tid = threadIdx.x;
    const int a = a0 + tid;
    const bool active = a < NA;

    __shared__ float s_gb[NG * 5];
    __shared__ float s_graw[NG][4];
    __shared__ int   s_lab[NG];
    __shared__ int   s_albl[256];
    __shared__ float s_aiou[256];

    if (tid < NG) {
        const float4 gb = *reinterpret_cast<const float4*>(gt_bboxes + ((size_t)b * NG + tid) * 4);
        s_graw[tid][0] = gb.x; s_graw[tid][1] = gb.y; s_graw[tid][2] = gb.z; s_graw[tid][3] = gb.w;
        const float gx1 = gb.x - gb.z * 0.5f, gy1 = gb.y - gb.w * 0.5f;
        const float gx2 = gb.x + gb.z * 0.5f, gy2 = gb.y + gb.w * 0.5f;
        s_gb[tid * 5 + 0] = gx1; s_gb[tid * 5 + 1] = gy1;
        s_gb[tid * 5 + 2] = gx2; s_gb[tid * 5 + 3] = gy2;
        s_gb[tid * 5 + 4] = (gx2 - gx1) * (gy2 - gy1);
        s_lab[tid] = gt_labels[b * NG + tid];
    }
    __syncthreads();

    unsigned long long cand = 0ull;
    if (active) cand = cand_mask[(size_t)b * NA + a];
    const bool fg = (cand != 0ull);

    int assigned = 0;
    float aiou = 0.0f;
    if (fg) {
        const float am = amax_arr[(size_t)b * NA + a];
        const int first = __ffsll(cand) - 1;
        int last = -1;
        unsigned long long rem = cand;
        while (rem) {
            const int g = __ffsll(rem) - 1;
            rem &= rem - 1;
            const float mv = metrics[((size_t)(b * NG + g)) * NA + a];
            if (mv >= am) last = g;           // reference last_max semantics
        }
        assigned = (last >= 0) ? last : first;
        const float4 pb = *reinterpret_cast<const float4*>(pd_bboxes + ((size_t)b * NA + a) * 4);
        const float px1 = pb.x - pb.z * 0.5f, py1 = pb.y - pb.w * 0.5f;
        const float px2 = pb.x + pb.z * 0.5f, py2 = pb.y + pb.w * 0.5f;
        const float ap = (px2 - px1) * (py2 - py1);
        aiou = iou_corners(px1, py1, px2, py2, ap,
                           s_gb[assigned*5+0], s_gb[assigned*5+1],
                           s_gb[assigned*5+2], s_gb[assigned*5+3], s_gb[assigned*5+4]);
    }

    s_albl[tid] = fg ? s_lab[assigned] : -1;
    s_aiou[tid] = fg ? aiou : 0.0f;

    if (active) {
        float4 ob = fg ? make_float4(s_graw[assigned][0], s_graw[assigned][1],
                                     s_graw[assigned][2], s_graw[assigned][3])
                       : make_float4(0.f, 0.f, 0.f, 0.f);
        *reinterpret_cast<float4*>(out + OFF_BBOX + ((size_t)b * NA + a) * 4) = ob;
        out[OFF_FG + (size_t)b * NA + a] = fg ? 1.0f : 0.0f;
    }
    __syncthreads();

    // one-hot label/score tiles, float4-vectorized
    const int cnt = min(256, NA - a0);
    float4* __restrict__ lblp = reinterpret_cast<float4*>(out + OFF_LBL + ((size_t)b * NA + a0) * NC);
    float4* __restrict__ scrp = reinterpret_cast<float4*>(out + OFF_SCR + ((size_t)b * NA + a0) * NC);
    for (int i4 = tid; i4 < cnt * 20; i4 += 256) {
        const int al = i4 / 20;
        const int cb = (i4 - al * 20) * 4;
        const int lbl = s_albl[al];
        const float aio = s_aiou[al];
        float4 l4, s4;
        l4.x = (cb + 0 == lbl) ? 1.0f : 0.0f;  s4.x = (cb + 0 == lbl) ? aio : 0.0f;
        l4.y = (cb + 1 == lbl) ? 1.0f : 0.0f;  s4.y = (cb + 1 == lbl) ? aio : 0.0f;
        l4.z = (cb + 2 == lbl) ? 1.0f : 0.0f;  s4.z = (cb + 2 == lbl) ? aio : 0.0f;
        l4.w = (cb + 3 == lbl) ? 1.0f : 0.0f;  s4.w = (cb + 3 == lbl) ? aio : 0.0f;
        lblp[i4] = l4;
        scrp[i4] = s4;
    }
}

// ================= fallback (round-2 verified path, 106 KB ws) =================
__global__ __launch_bounds__(256) void topk_fb(
    const float* __restrict__ pd_scores, const float* __restrict__ pd_bboxes,
    const int* __restrict__ gt_labels, const float* __restrict__ gt_bboxes,
    const int* __restrict__ mask_gt, int* __restrict__ topk_idx)
{
    const int g = blockIdx.x, b = blockIdx.y, tid = threadIdx.x;
    int* outp = topk_idx + (b * NG + g) * NK;
    if (mask_gt[b * NG + g] == 0) { if (tid < NK) outp[tid] = -1; return; }
    __shared__ float sm[NA];
    __shared__ float wv[4]; __shared__ int wi[4];
    const int label = gt_labels[b * NG + g];
    const float4 gb = *reinterpret_cast<const float4*>(gt_bboxes + (size_t)(b * NG + g) * 4);
    const float gx1 = gb.x - gb.z * 0.5f, gy1 = gb.y - gb.w * 0.5f;
    const float gx2 = gb.x + gb.z * 0.5f, gy2 = gb.y + gb.w * 0.5f;
    const float ag = (gx2 - gx1) * (gy2 - gy1);
    for (int a = tid; a < NA; a += 256) {
        const float4 pb = *reinterpret_cast<const float4*>(pd_bboxes + ((size_t)b * NA + a) * 4);
        const float px1 = pb.x - pb.z * 0.5f, py1 = pb.y - pb.w * 0.5f;
        const float px2 = pb.x + pb.z * 0.5f, py2 = pb.y + pb.w * 0.5f;
        const float ap = (px2 - px1) * (py2 - py1);
        const float iou = iou_corners(px1, py1, px2, py2, ap, gx1, gy1, gx2, gy2, ag);
        const float s = pd_scores[((size_t)b * NA + a) * NC + label];
        const float i2 = iou * iou;
        sm[a] = sigmoid_f(s) * (i2 * i2 * i2);
    }
    __syncthreads();
    for (int k = 0; k < NK; ++k) {
        float bv = -3.0f; int bi = 0x7fffffff;
        for (int a = tid; a < NA; a += 256) {
            const float vv = sm[a];
            if (vv > bv || (vv == bv && a < bi)) { bv = vv; bi = a; }
        }
        #pragma unroll
        for (int off = 32; off; off >>= 1) {
            const float ov = __shfl_xor(bv, off); const int oi = __shfl_xor(bi, off);
            if (ov > bv || (ov == bv && oi < bi)) { bv = ov; bi = oi; }
        }
        if ((tid & 63) == 0) { wv[tid >> 6] = bv; wi[tid >> 6] = bi; }
        __syncthreads();
        if (tid == 0) {
            #pragma unroll
            for (int w = 1; w < 4; ++w)
                if (wv[w] > bv || (wv[w] == bv && wi[w] < bi)) { bv = wv[w]; bi = wi[w]; }
            outp[k] = bi; sm[bi] = -2.0f;
        }
        __syncthreads();
    }
}

__global__ __launch_bounds__(256) void assign_fb(
    const float* __restrict__ pd_scores, const float* __restrict__ pd_bboxes,
    const int* __restrict__ gt_labels, const float* __restrict__ gt_bboxes,
    const int* __restrict__ mask_gt, const int* __restrict__ topk_idx,
    float* __restrict__ out)
{
    const int b = blockIdx.y, a0 = blockIdx.x * 256, tid = threadIdx.x;
    __shared__ float s_gx1[NG], s_gy1[NG], s_gx2[NG], s_gy2[NG], s_gar[NG];
    __shared__ float s_graw[NG][4];
    __shared__ int s_lab[NG], s_val[NG], s_tk[NG][NK], s_albl[256];
    __shared__ float s_aiou[256];
    if (tid < NG) {
        const float4 gb = *reinterpret_cast<const float4*>(gt_bboxes + ((size_t)b * NG + tid) * 4);
        s_graw[tid][0] = gb.x; s_graw[tid][1] = gb.y; s_graw[tid][2] = gb.z; s_graw[tid][3] = gb.w;
        const float gx1 = gb.x - gb.z * 0.5f, gy1 = gb.y - gb.w * 0.5f;
        const float gx2 = gb.x + gb.z * 0.5f, gy2 = gb.y + gb.w * 0.5f;
        s_gx1[tid] = gx1; s_gy1[tid] = gy1; s_gx2[tid] = gx2; s_gy2[tid] = gy2;
        s_gar[tid] = (gx2 - gx1) * (gy2 - gy1);
        s_lab[tid] = gt_labels[b * NG + tid];
        s_val[tid] = mask_gt[b * NG + tid];
    }
    for (int i = tid; i < NG * NK; i += 256) s_tk[i / NK][i % NK] = topk_idx[(size_t)b * NG * NK + i];
    __syncthreads();
    const int a = a0 + tid;
    const bool active = a < NA;
    float anchor_max = -1.0f;
    unsigned long long cand = 0ull;
    float px1 = 0, py1 = 0, px2 = 0, py2 = 0, ap = 0;
    const float* srow = pd_scores + ((size_t)b * NA + a) * NC;
    if (active) {
        const float4 pb = *reinterpret_cast<const float4*>(pd_bboxes + ((size_t)b * NA + a) * 4);
        px1 = pb.x - pb.z * 0.5f; py1 = pb.y - pb.w * 0.5f;
        px2 = pb.x + pb.z * 0.5f; py2 = pb.y + pb.w * 0.5f;
        ap = (px2 - px1) * (py2 - py1);
        for (int g = 0; g < NG; ++g) {
            if (!s_val[g]) continue;
            const float iou = iou_corners(px1, py1, px2, py2, ap, s_gx1[g], s_gy1[g], s_gx2[g], s_gy2[g], s_gar[g]);
            const float i2 = iou * iou;
            const float m = sigmoid_f(srow[s_lab[g]]) * (i2 * i2 * i2);
            anchor_max = fmaxf(anchor_max, m);
            bool c = false;
            #pragma unroll
            for (int k = 0; k < NK; ++k) c = c || (s_tk[g][k] == a);
            if (c) cand |= (1ull << g);
        }
    }
    const bool fg = (cand != 0ull);
    int assigned = 0; float aiou = 0.0f;
    if (fg) {
        const int first = __ffsll(cand) - 1;
        int lastg = -1;
        unsigned long long rem = cand;
        while (rem) {
            const int g = __ffsll(rem) - 1; rem &= rem - 1;
            const float iou = iou_corners(px1, py1, px2, py2, ap, s_gx1[g], s_gy1[g], s_gx2[g], s_gy2[g], s_gar[g]);
            const float i2 = iou * iou;
            const float m = sigmoid_f(srow[s_lab[g]]) * (i2 * i2 * i2);
            if (m >= anchor_max) lastg = g;
        }
        assigned = (lastg >= 0) ? lastg : first;
        aiou = iou_corners(px1, py1, px2, py2, ap, s_gx1[assigned], s_gy1[assigned], s_gx2[assigned], s_gy2[assigned], s_gar[assigned]);
    }
    s_albl[tid] = fg ? s_lab[assigned] : -1;
    s_aiou[tid] = fg ? aiou : 0.0f;
    if (active) {
        float4 ob = fg ? make_float4(s_graw[assigned][0], s_graw[assigned][1], s_graw[assigned][2], s_graw[assigned][3])
                       : make_float4(0.f, 0.f, 0.f, 0.f);
        *reinterpret_cast<float4*>(out + OFF_BBOX + ((size_t)b * NA + a) * 4) = ob;
        out[OFF_FG + (size_t)b * NA + a] = fg ? 1.0f : 0.0f;
    }
    __syncthreads();
    const int cnt = min(256, NA - a0);
    for (int i = tid; i < cnt * NC; i += 256) {
        const int al = i / NC, c = i - al * NC;
        const int lbl = s_albl[al];
        const size_t base = ((size_t)b * NA + (a0 + al)) * NC + c;
        out[OFF_LBL + base] = (c == lbl) ? 1.0f : 0.0f;
        out[OFF_SCR + base] = (c == lbl) ? s_aiou[al] : 0.0f;
    }
}

extern "C" void kernel_launch(void* const* d_in, const int* in_sizes, int n_in,
                              void* d_out, int out_size, void* d_ws, size_t ws_size,
                              hipStream_t stream) {
    const float* pd_scores = (const float*)d_in[0];
    const float* pd_bboxes = (const float*)d_in[1];
    const int*   gt_labels = (const int*)d_in[3];
    const float* gt_bboxes = (const float*)d_in[4];
    const int*   mask_gt   = (const int*)d_in[5];
    float* out = (float*)d_out;

    if (ws_size >= WS_NEEDED) {
        float* metrics = (float*)d_ws;
        unsigned long long* cmask = (unsigned long long*)((char*)d_ws + WS_METRICS_SZ);
        float* amax_arr = (float*)((char*)d_ws + WS_METRICS_SZ + WS_MASK_SZ);

        dim3 g0(NT0, NB);
        metrics_kernel<<<g0, 256, 0, stream>>>(pd_scores, pd_bboxes, gt_labels, gt_bboxes,
                                               mask_gt, metrics, amax_arr, cmask);

        dim3 g1(NG, NB);
        topk_kernel<<<g1, 256, 0, stream>>>(metrics, mask_gt, cmask);

        dim3 g2((NA + 255) / 256, NB);
        assign_kernel<<<g2, 256, 0, stream>>>(metrics, amax_arr, pd_bboxes, gt_labels, gt_bboxes,
                                              cmask, out);
    } else {
        int* topk = (int*)d_ws;
        dim3 g1(NG, NB);
        topk_fb<<<g1, 256, 0, stream>>>(pd_scores, pd_bboxes, gt_labels, gt_bboxes, mask_gt, topk);
        dim3 g2((NA + 255) / 256, NB);
        assign_fb<<<g2, 256, 0, stream>>>(pd_scores, pd_bboxes, gt_labels, gt_bboxes, mask_gt, topk, out);
    }
}

// Round 5
// 322.647 us; speedup vs baseline: 1.8182x; 1.1398x over previous
//
#include <hip/hip_runtime.h>

#define NB 32
#define NA 8400
#define NG 64
#define NC 80
#define NK 13
#define TILE0 64
#define NT0 132          // ceil(8400/64); last tile has 16 anchors (>= NK, required)

// output offsets (floats) in d_out
#define OFF_LBL  0
#define OFF_BBOX 21504000
#define OFF_SCR  22579200
#define OFF_FG   44083200

// ws layout (bytes)
#define WS_PART_SZ  (32ull*64*132*13*8)   // 28,114,944  partial top-13 (float2: v, idx)
#define WS_MASK_SZ  (32ull*8400*8)        //  2,150,400  cand bitmask
#define WS_AMAX_SZ  (32ull*8400*4)        //  1,075,200  per-anchor max metric
#define WS_MAXB_SZ  (32ull*8400*8)        //  2,150,400  is_max_cand bitmask
#define WS_NEEDED   (WS_PART_SZ + WS_MASK_SZ + WS_AMAX_SZ + WS_MAXB_SZ)

__device__ __forceinline__ float sigmoid_f(float x) {
    return 1.0f / (1.0f + expf(-x));
}

__device__ __forceinline__ float iou_corners(
    float px1, float py1, float px2, float py2, float ap,
    float gx1, float gy1, float gx2, float gy2, float ag)
{
    float ix1 = fmaxf(px1, gx1), iy1 = fmaxf(py1, gy1);
    float ix2 = fminf(px2, gx2), iy2 = fminf(py2, gy2);
    float inter = fmaxf(ix2 - ix1, 0.0f) * fmaxf(iy2 - iy1, 0.0f);
    return inter / (ap + ag - inter + 1e-7f);
}

// ==== K0: per-(b, 64-anchor tile): tile-local top-13 per g + amax + mask zeroing ====
__global__ __launch_bounds__(256) void metrics_kernel(
    const float* __restrict__ pd_scores,   // [B,A,C]
    const float* __restrict__ pd_bboxes,   // [B,A,4]
    const int* __restrict__ gt_labels,     // [B,G]
    const float* __restrict__ gt_bboxes,   // [B,G,4]
    const int* __restrict__ mask_gt,       // [B,G] (bool as int32)
    float2* __restrict__ partials,         // [B,G,NT0,13] (v, idx-bits)
    float* __restrict__ amax_arr,          // [B,A]
    unsigned long long* __restrict__ cmask,   // [B,A] zeroed here
    unsigned long long* __restrict__ maxbits) // [B,A] zeroed here
{
    const int b   = blockIdx.y;
    const int til = blockIdx.x;
    const int a0  = til * TILE0;
    const int tid = threadIdx.x;
    const int an  = min(TILE0, NA - a0);

    __shared__ float s_sc[TILE0 * 81];   // sigmoid(scores), pad 81 -> conflict-free
    __shared__ float s_pb[TILE0 * 5];    // px1,py1,px2,py2,area
    __shared__ float s_gb[NG * 5];
    __shared__ float s_pm[4][TILE0];
    __shared__ int   s_lab[NG];
    __shared__ int   s_val[NG];

    const float* sbase = pd_scores + ((size_t)b * NA + a0) * NC;
    for (int i4 = tid; i4 < an * 20; i4 += 256) {
        const float4 v = reinterpret_cast<const float4*>(sbase)[i4];
        const int al = i4 / 20;
        const int c  = (i4 % 20) * 4;
        float* d = &s_sc[al * 81 + c];
        d[0] = sigmoid_f(v.x); d[1] = sigmoid_f(v.y);
        d[2] = sigmoid_f(v.z); d[3] = sigmoid_f(v.w);
    }
    if (tid < TILE0) {   // pad lanes get zeros (safe math; their m is forced to -1)
        float px1 = 0, py1 = 0, px2 = 0, py2 = 0;
        if (tid < an) {
            const float4 pb = *reinterpret_cast<const float4*>(pd_bboxes + ((size_t)b * NA + a0 + tid) * 4);
            px1 = pb.x - pb.z * 0.5f; py1 = pb.y - pb.w * 0.5f;
            px2 = pb.x + pb.z * 0.5f; py2 = pb.y + pb.w * 0.5f;
        }
        s_pb[tid * 5 + 0] = px1; s_pb[tid * 5 + 1] = py1;
        s_pb[tid * 5 + 2] = px2; s_pb[tid * 5 + 3] = py2;
        s_pb[tid * 5 + 4] = (px2 - px1) * (py2 - py1);
    }
    if (tid >= 64 && tid < 64 + NG) {
        const int g = tid - 64;
        const float4 gb = *reinterpret_cast<const float4*>(gt_bboxes + ((size_t)b * NG + g) * 4);
        const float gx1 = gb.x - gb.z * 0.5f, gy1 = gb.y - gb.w * 0.5f;
        const float gx2 = gb.x + gb.z * 0.5f, gy2 = gb.y + gb.w * 0.5f;
        s_gb[g * 5 + 0] = gx1; s_gb[g * 5 + 1] = gy1;
        s_gb[g * 5 + 2] = gx2; s_gb[g * 5 + 3] = gy2;
        s_gb[g * 5 + 4] = (gx2 - gx1) * (gy2 - gy1);
        s_lab[g] = gt_labels[b * NG + g];
        s_val[g] = mask_gt[b * NG + g];
    }
    __syncthreads();

    const int lane = tid & 63;          // anchor within tile
    const int wgrp = tid >> 6;
    const float px1 = s_pb[lane * 5 + 0], py1 = s_pb[lane * 5 + 1];
    const float px2 = s_pb[lane * 5 + 2], py2 = s_pb[lane * 5 + 3];
    const float ap  = s_pb[lane * 5 + 4];
    float pm = -1.0f;

    #pragma unroll 4
    for (int gg = 0; gg < 16; ++gg) {
        const int g = gg * 4 + wgrp;
        float m = -1.0f;                // pad lanes / invalid g: excluded sentinel
        if (lane < an && s_val[g]) {
            const float iou = iou_corners(px1, py1, px2, py2, ap,
                                          s_gb[g*5+0], s_gb[g*5+1], s_gb[g*5+2], s_gb[g*5+3], s_gb[g*5+4]);
            const float i2 = iou * iou;
            m = s_sc[lane * 81 + s_lab[g]] * (i2 * i2 * i2);
        }
        pm = fmaxf(pm, m);

        // --- wave-level tile top-13 under (v desc, idx asc) ---
        const unsigned long long pos = __ballot(m > 0.0f);
        const unsigned long long zer = __ballot(m == 0.0f);
        const int n = __popcll(pos);
        int slot = -1;
        if (m > 0.0f) {
            int r = 0;
            unsigned long long rem = pos;
            while (rem) {
                const int j = __ffsll(rem) - 1;
                rem &= rem - 1;
                const float vj = __shfl(m, j);
                r += (vj > m || (vj == m && j < lane)) ? 1 : 0;
            }
            if (r < NK) slot = r;       // exact top-13 among positives
        } else if (m == 0.0f && n < NK) {
            const int p = __popcll(zer & ((1ull << lane) - 1ull));
            if (p < NK - n) slot = n + p;   // lowest-index zeros fill the rest
        }
        if (slot >= 0) {
            float2 e; e.x = m; e.y = __int_as_float(a0 + lane);
            partials[(((size_t)(b * NG + g)) * NT0 + til) * NK + slot] = e;
        }
    }

    s_pm[wgrp][lane] = pm;
    __syncthreads();
    if (tid < an) {
        const float am = fmaxf(fmaxf(s_pm[0][tid], s_pm[1][tid]),
                               fmaxf(s_pm[2][tid], s_pm[3][tid]));
        amax_arr[(size_t)b * NA + a0 + tid] = am;
        cmask[(size_t)b * NA + a0 + tid]   = 0ull;
        maxbits[(size_t)b * NA + a0 + tid] = 0ull;
    }
}

// ==== K1: merge 132 partials -> global top-13 per (b,g); set cand + maxbit ====
__global__ __launch_bounds__(256) void merge_kernel(
    const float2* __restrict__ partials,
    const float* __restrict__ amax_arr,
    const int* __restrict__ mask_gt,
    unsigned long long* __restrict__ cmask,
    unsigned long long* __restrict__ maxbits)
{
    const int g = blockIdx.x;
    const int b = blockIdx.y;
    const int tid = threadIdx.x;

    if (mask_gt[b * NG + g] == 0) return;   // invalid g: no partials written, no bits

    const float2* __restrict__ row = partials + ((size_t)(b * NG + g)) * NT0 * NK;

    float v[NK]; int ix[NK];
    #pragma unroll
    for (int k = 0; k < NK; ++k) { v[k] = -3.0f; ix[k] = 0x7fffffff; }

    // per-thread stream visits entries in increasing tile order -> on equal values
    // the earlier (lower-anchor) entry stays ahead under strict '>' insertion
    for (int i = tid; i < NT0 * NK; i += 256) {
        const float2 e = row[i];
        float m = e.x;
        int   a = __float_as_int(e.y);
        if (m > v[NK-1]) {
            #pragma unroll
            for (int k = 0; k < NK; ++k) {
                if (m > v[k]) {
                    const float tv = v[k]; v[k] = m;  m = tv;
                    const int   ti = ix[k]; ix[k] = a; a = ti;
                }
            }
        }
    }

    __shared__ float s_wv[4];
    __shared__ int   s_wi[4];
    __shared__ int   s_sel[NK];
    __shared__ float s_selv[NK];

    for (int r = 0; r < NK; ++r) {
        float bv = v[0]; int bi = ix[0];
        #pragma unroll
        for (int off = 32; off; off >>= 1) {
            const float ov = __shfl_xor(bv, off);
            const int   oi = __shfl_xor(bi, off);
            if (ov > bv || (ov == bv && oi < bi)) { bv = ov; bi = oi; }
        }
        if ((tid & 63) == 0) { s_wv[tid >> 6] = bv; s_wi[tid >> 6] = bi; }
        __syncthreads();
        bv = s_wv[0]; bi = s_wi[0];
        #pragma unroll
        for (int w = 1; w < 4; ++w) {
            if (s_wv[w] > bv || (s_wv[w] == bv && s_wi[w] < bi)) { bv = s_wv[w]; bi = s_wi[w]; }
        }
        if (tid == 0) { s_sel[r] = bi; s_selv[r] = bv; }
        if (v[0] == bv && ix[0] == bi) {      // unique anchor -> exactly one popper
            #pragma unroll
            for (int k = 0; k < NK - 1; ++k) { v[k] = v[k+1]; ix[k] = ix[k+1]; }
            v[NK-1] = -3.0f; ix[NK-1] = 0x7fffffff;
        }
        __syncthreads();
    }

    if (tid < NK) {
        const int a = s_sel[tid];
        atomicOr(&cmask[(size_t)b * NA + a], 1ull << g);
        if (s_selv[tid] >= amax_arr[(size_t)b * NA + a]) {
            atomicOr(&maxbits[(size_t)b * NA + a], 1ull << g);
        }
    }
}

// ==== K2: per-anchor resolve from two bitmasks + outputs ====
__global__ __launch_bounds__(256) void assign_kernel(
    const float* __restrict__ pd_bboxes,
    const int* __restrict__ gt_labels,
    const float* __restrict__ gt_bboxes,
    const unsigned long long* __restrict__ cmask,
    const unsigned long long* __restrict__ maxbits,
    float* __restrict__ out)
{
    const int b = blockIdx.y;
    const int a0 = blockIdx.x * 256;
    const int tid = threadIdx.x;
    const int a = a0 + tid;
    const bool active = a < NA;

    __shared__ float s_gb[NG * 5];
    __shared__ float s_graw[NG][4];
    __shared__ int   s_lab[NG];
    __shared__ int   s_albl[256];
    __shared__ float s_aiou[256];

    if (tid < NG) {
        const float4 gb = *reinterpret_cast<const float4*>(gt_bboxes + ((size_t)b * NG + tid) * 4);
        s_graw[tid][0] = gb.x; s_graw[tid][1] = gb.y; s_graw[tid][2] = gb.z; s_graw[tid][3] = gb.w;
        const float gx1 = gb.x - gb.z * 0.5f, gy1 = gb.y - gb.w * 0.5f;
        const float gx2 = gb.x + gb.z * 0.5f, gy2 = gb.y + gb.w * 0.5f;
        s_gb[tid * 5 + 0] = gx1; s_gb[tid * 5 + 1] = gy1;
        s_gb[tid * 5 + 2] = gx2; s_gb[tid * 5 + 3] = gy2;
        s_gb[tid * 5 + 4] = (gx2 - gx1) * (gy2 - gy1);
        s_lab[tid] = gt_labels[b * NG + tid];
    }
    __syncthreads();

    unsigned long long cand = 0ull, maxb = 0ull;
    if (active) {
        cand = cmask[(size_t)b * NA + a];
        maxb = maxbits[(size_t)b * NA + a];
    }
    const bool fg = (cand != 0ull);

    int assigned = 0;
    float aiou = 0.0f;
    if (fg) {
        // reference: last g with (metric >= anchor_max) among candidates, else first candidate
        assigned = maxb ? (63 - __clzll(maxb)) : (__ffsll(cand) - 1);
        const float4 pb = *reinterpret_cast<const float4*>(pd_bboxes + ((size_t)b * NA + a) * 4);
        const float px1 = pb.x - pb.z * 0.5f, py1 = pb.y - pb.w * 0.5f;
        const float px2 = pb.x + pb.z * 0.5f, py2 = pb.y + pb.w * 0.5f;
        const float ap = (px2 - px1) * (py2 - py1);
        aiou = iou_corners(px1, py1, px2, py2, ap,
                           s_gb[assigned*5+0], s_gb[assigned*5+1],
                           s_gb[assigned*5+2], s_gb[assigned*5+3], s_gb[assigned*5+4]);
    }

    s_albl[tid] = fg ? s_lab[assigned] : -1;
    s_aiou[tid] = fg ? aiou : 0.0f;

    if (active) {
        float4 ob = fg ? make_float4(s_graw[assigned][0], s_graw[assigned][1],
                                     s_graw[assigned][2], s_graw[assigned][3])
                       : make_float4(0.f, 0.f, 0.f, 0.f);
        *reinterpret_cast<float4*>(out + OFF_BBOX + ((size_t)b * NA + a) * 4) = ob;
        out[OFF_FG + (size_t)b * NA + a] = fg ? 1.0f : 0.0f;
    }
    __syncthreads();

    const int cnt = min(256, NA - a0);
    float4* __restrict__ lblp = reinterpret_cast<float4*>(out + OFF_LBL + ((size_t)b * NA + a0) * NC);
    float4* __restrict__ scrp = reinterpret_cast<float4*>(out + OFF_SCR + ((size_t)b * NA + a0) * NC);
    for (int i4 = tid; i4 < cnt * 20; i4 += 256) {
        const int al = i4 / 20;
        const int cb = (i4 - al * 20) * 4;
        const int lbl = s_albl[al];
        const float aio = s_aiou[al];
        float4 l4, s4;
        l4.x = (cb + 0 == lbl) ? 1.0f : 0.0f;  s4.x = (cb + 0 == lbl) ? aio : 0.0f;
        l4.y = (cb + 1 == lbl) ? 1.0f : 0.0f;  s4.y = (cb + 1 == lbl) ? aio : 0.0f;
        l4.z = (cb + 2 == lbl) ? 1.0f : 0.0f;  s4.z = (cb + 2 == lbl) ? aio : 0.0f;
        l4.w = (cb + 3 == lbl) ? 1.0f : 0.0f;  s4.w = (cb + 3 == lbl) ? aio : 0.0f;
        lblp[i4] = l4;
        scrp[i4] = s4;
    }
}

// ================= fallback (round-2 verified path, 106 KB ws) =================
__global__ __launch_bounds__(256) void topk_fb(
    const float* __restrict__ pd_scores, const float* __restrict__ pd_bboxes,
    const int* __restrict__ gt_labels, const float* __restrict__ gt_bboxes,
    const int* __restrict__ mask_gt, int* __restrict__ topk_idx)
{
    const int g = blockIdx.x, b = blockIdx.y, tid = threadIdx.x;
    int* outp = topk_idx + (b * NG + g) * NK;
    if (mask_gt[b * NG + g] == 0) { if (tid < NK) outp[tid] = -1; return; }
    __shared__ float sm[NA];
    __shared__ float wv[4]; __shared__ int wi[4];
    const int label = gt_labels[b * NG + g];
    const float4 gb = *reinterpret_cast<const float4*>(gt_bboxes + (size_t)(b * NG + g) * 4);
    const float gx1 = gb.x - gb.z * 0.5f, gy1 = gb.y - gb.w * 0.5f;
    const float gx2 = gb.x + gb.z * 0.5f, gy2 = gb.y + gb.w * 0.5f;
    const float ag = (gx2 - gx1) * (gy2 - gy1);
    for (int a = tid; a < NA; a += 256) {
        const float4 pb = *reinterpret_cast<const float4*>(pd_bboxes + ((size_t)b * NA + a) * 4);
        const float px1 = pb.x - pb.z * 0.5f, py1 = pb.y - pb.w * 0.5f;
        const float px2 = pb.x + pb.z * 0.5f, py2 = pb.y + pb.w * 0.5f;
        const float ap = (px2 - px1) * (py2 - py1);
        const float iou = iou_corners(px1, py1, px2, py2, ap, gx1, gy1, gx2, gy2, ag);
        const float s = pd_scores[((size_t)b * NA + a) * NC + label];
        const float i2 = iou * iou;
        sm[a] = sigmoid_f(s) * (i2 * i2 * i2);
    }
    __syncthreads();
    for (int k = 0; k < NK; ++k) {
        float bv = -3.0f; int bi = 0x7fffffff;
        for (int a = tid; a < NA; a += 256) {
            const float vv = sm[a];
            if (vv > bv || (vv == bv && a < bi)) { bv = vv; bi = a; }
        }
        #pragma unroll
        for (int off = 32; off; off >>= 1) {
            const float ov = __shfl_xor(bv, off); const int oi = __shfl_xor(bi, off);
            if (ov > bv || (ov == bv && oi < bi)) { bv = ov; bi = oi; }
        }
        if ((tid & 63) == 0) { wv[tid >> 6] = bv; wi[tid >> 6] = bi; }
        __syncthreads();
        if (tid == 0) {
            #pragma unroll
            for (int w = 1; w < 4; ++w)
                if (wv[w] > bv || (wv[w] == bv && wi[w] < bi)) { bv = wv[w]; bi = wi[w]; }
            outp[k] = bi; sm[bi] = -2.0f;
        }
        __syncthreads();
    }
}

__global__ __launch_bounds__(256) void assign_fb(
    const float* __restrict__ pd_scores, const float* __restrict__ pd_bboxes,
    const int* __restrict__ gt_labels, const float* __restrict__ gt_bboxes,
    const int* __restrict__ mask_gt, const int* __restrict__ topk_idx,
    float* __restrict__ out)
{
    const int b = blockIdx.y, a0 = blockIdx.x * 256, tid = threadIdx.x;
    __shared__ float s_gx1[NG], s_gy1[NG], s_gx2[NG], s_gy2[NG], s_gar[NG];
    __shared__ float s_graw[NG][4];
    __shared__ int s_lab[NG], s_val[NG], s_tk[NG][NK], s_albl[256];
    __shared__ float s_aiou[256];
    if (tid < NG) {
        const float4 gb = *reinterpret_cast<const float4*>(gt_bboxes + ((size_t)b * NG + tid) * 4);
        s_graw[tid][0] = gb.x; s_graw[tid][1] = gb.y; s_graw[tid][2] = gb.z; s_graw[tid][3] = gb.w;
        const float gx1 = gb.x - gb.z * 0.5f, gy1 = gb.y - gb.w * 0.5f;
        const float gx2 = gb.x + gb.z * 0.5f, gy2 = gb.y + gb.w * 0.5f;
        s_gx1[tid] = gx1; s_gy1[tid] = gy1; s_gx2[tid] = gx2; s_gy2[tid] = gy2;
        s_gar[tid] = (gx2 - gx1) * (gy2 - gy1);
        s_lab[tid] = gt_labels[b * NG + tid];
        s_val[tid] = mask_gt[b * NG + tid];
    }
    for (int i = tid; i < NG * NK; i += 256) s_tk[i / NK][i % NK] = topk_idx[(size_t)b * NG * NK + i];
    __syncthreads();
    const int a = a0 + tid;
    const bool active = a < NA;
    float anchor_max = -1.0f;
    unsigned long long cand = 0ull;
    float px1 = 0, py1 = 0, px2 = 0, py2 = 0, ap = 0;
    const float* srow = pd_scores + ((size_t)b * NA + a) * NC;
    if (active) {
        const float4 pb = *reinterpret_cast<const float4*>(pd_bboxes + ((size_t)b * NA + a) * 4);
        px1 = pb.x - pb.z * 0.5f; py1 = pb.y - pb.w * 0.5f;
        px2 = pb.x + pb.z * 0.5f; py2 = pb.y + pb.w * 0.5f;
        ap = (px2 - px1) * (py2 - py1);
        for (int g = 0; g < NG; ++g) {
            if (!s_val[g]) continue;
            const float iou = iou_corners(px1, py1, px2, py2, ap, s_gx1[g], s_gy1[g], s_gx2[g], s_gy2[g], s_gar[g]);
            const float i2 = iou * iou;
            const float m = sigmoid_f(srow[s_lab[g]]) * (i2 * i2 * i2);
            anchor_max = fmaxf(anchor_max, m);
            bool c = false;
            #pragma unroll
            for (int k = 0; k < NK; ++k) c = c || (s_tk[g][k] == a);
            if (c) cand |= (1ull << g);
        }
    }
    const bool fg = (cand != 0ull);
    int assigned = 0; float aiou = 0.0f;
    if (fg) {
        const int first = __ffsll(cand) - 1;
        int lastg = -1;
        unsigned long long rem = cand;
        while (rem) {
            const int g = __ffsll(rem) - 1; rem &= rem - 1;
            const float iou = iou_corners(px1, py1, px2, py2, ap, s_gx1[g], s_gy1[g], s_gx2[g], s_gy2[g], s_gar[g]);
            const float i2 = iou * iou;
            const float m = sigmoid_f(srow[s_lab[g]]) * (i2 * i2 * i2);
            if (m >= anchor_max) lastg = g;
        }
        assigned = (lastg >= 0) ? lastg : first;
        aiou = iou_corners(px1, py1, px2, py2, ap, s_gx1[assigned], s_gy1[assigned], s_gx2[assigned], s_gy2[assigned], s_gar[assigned]);
    }
    s_albl[tid] = fg ? s_lab[assigned] : -1;
    s_aiou[tid] = fg ? aiou : 0.0f;
    if (active) {
        float4 ob = fg ? make_float4(s_graw[assigned][0], s_graw[assigned][1], s_graw[assigned][2], s_graw[assigned][3])
                       : make_float4(0.f, 0.f, 0.f, 0.f);
        *reinterpret_cast<float4*>(out + OFF_BBOX + ((size_t)b * NA + a) * 4) = ob;
        out[OFF_FG + (size_t)b * NA + a] = fg ? 1.0f : 0.0f;
    }
    __syncthreads();
    const int cnt = min(256, NA - a0);
    for (int i = tid; i < cnt * NC; i += 256) {
        const int al = i / NC, c = i - al * NC;
        const int lbl = s_albl[al];
        const size_t base = ((size_t)b * NA + (a0 + al)) * NC + c;
        out[OFF_LBL + base] = (c == lbl) ? 1.0f : 0.0f;
        out[OFF_SCR + base] = (c == lbl) ? s_aiou[al] : 0.0f;
    }
}

extern "C" void kernel_launch(void* const* d_in, const int* in_sizes, int n_in,
                              void* d_out, int out_size, void* d_ws, size_t ws_size,
                              hipStream_t stream) {
    const float* pd_scores = (const float*)d_in[0];
    const float* pd_bboxes = (const float*)d_in[1];
    const int*   gt_labels = (const int*)d_in[3];
    const float* gt_bboxes = (const float*)d_in[4];
    const int*   mask_gt   = (const int*)d_in[5];
    float* out = (float*)d_out;

    if (ws_size >= WS_NEEDED) {
        float2* partials = (float2*)d_ws;
        unsigned long long* cmask = (unsigned long long*)((char*)d_ws + WS_PART_SZ);
        float* amax_arr = (float*)((char*)d_ws + WS_PART_SZ + WS_MASK_SZ);
        unsigned long long* maxbits = (unsigned long long*)((char*)d_ws + WS_PART_SZ + WS_MASK_SZ + WS_AMAX_SZ);

        dim3 g0(NT0, NB);
        metrics_kernel<<<g0, 256, 0, stream>>>(pd_scores, pd_bboxes, gt_labels, gt_bboxes,
                                               mask_gt, partials, amax_arr, cmask, maxbits);

        dim3 g1(NG, NB);
        merge_kernel<<<g1, 256, 0, stream>>>(partials, amax_arr, mask_gt, cmask, maxbits);

        dim3 g2((NA + 255) / 256, NB);
        assign_kernel<<<g2, 256, 0, stream>>>(pd_bboxes, gt_labels, gt_bboxes, cmask, maxbits, out);
    } else {
        int* topk = (int*)d_ws;
        dim3 g1(NG, NB);
        topk_fb<<<g1, 256, 0, stream>>>(pd_scores, pd_bboxes, gt_labels, gt_bboxes, mask_gt, topk);
        dim3 g2((NA + 255) / 256, NB);
        assign_fb<<<g2, 256, 0, stream>>>(pd_scores, pd_bboxes, gt_labels, gt_bboxes, mask_gt, topk, out);
    }
}